// Round 5
// baseline (287.832 us; speedup 1.0000x reference)
//
#include <hip/hip_runtime.h>
#include <math.h>

#define F_IN 128
#define H_DIM 64
#define C_OUT 40
#define NBK 391          // ceil(100000/256) coarse buckets, 256 nodes each
#define CHUNK 4096       // edges per binscatter block
#define XPAD 136         // padded LDS half-stride (128 + 8) -> bank spread
#define PHB 128          // partial-histogram blocks (stateless CSR build, no memset)

typedef _Float16 h8 __attribute__((ext_vector_type(8)));   // 16B = 8 fp16 features
typedef _Float16 half2t __attribute__((ext_vector_type(2)));
typedef float nf4 __attribute__((ext_vector_type(4)));     // native float4 (nt-load-able)
typedef _Float16 f16x8 __attribute__((ext_vector_type(8)));
typedef float f32x4 __attribute__((ext_vector_type(4)));

union H8 {
    h8 v;
    half2t p[4];
};

__device__ __forceinline__ float dot8(const H8& a, const H8& b) {
    float d = __builtin_amdgcn_fdot2(a.p[0], b.p[0], 0.0f, false);
    d = __builtin_amdgcn_fdot2(a.p[1], b.p[1], d, false);
    d = __builtin_amdgcn_fdot2(a.p[2], b.p[2], d, false);
    d = __builtin_amdgcn_fdot2(a.p[3], b.p[3], d, false);
    return d;
}

// Butterfly add across the 8 sub-lanes (lane bits 0..2) using DPP only:
// xor1 = quad_perm(1,0,3,2)=0xB1, xor2 = quad_perm(2,3,0,1)=0x4E,
// cross-quad = row_half_mirror (0x141; valid since quads are uniform by then).
__device__ __forceinline__ float dpp_red8_add(float x) {
    int v = __builtin_bit_cast(int, x);
    x += __builtin_bit_cast(float, __builtin_amdgcn_update_dpp(0, v, 0xB1, 0xF, 0xF, true));
    v = __builtin_bit_cast(int, x);
    x += __builtin_bit_cast(float, __builtin_amdgcn_update_dpp(0, v, 0x4E, 0xF, 0xF, true));
    v = __builtin_bit_cast(int, x);
    x += __builtin_bit_cast(float, __builtin_amdgcn_update_dpp(0, v, 0x141, 0xF, 0xF, true));
    return x;
}

// ---------------- CSR build: two-level LDS counting sort ----------------
// pairs packed: (dst&255)<<24 | src   (src < 2^17)

// Stateless partial histogram: each block fully writes its own 512-bin slice
// (plain stores) -> no pre-zeroed global memory, no hipMemsetAsync.
__global__ void __launch_bounds__(256) bphist_kernel(const int* __restrict__ dst,
                                                     int* __restrict__ part, int E) {
    __shared__ int lh[512];
    int tid = threadIdx.x;
    lh[tid] = 0; lh[tid + 256] = 0;
    __syncthreads();
    int slice = (E + PHB - 1) / PHB;
    int lo = blockIdx.x * slice;
    int hi = min(E, lo + slice);
    for (int e = lo + tid; e < hi; e += 256) {
        int d = __builtin_nontemporal_load(&dst[e]);
        atomicAdd(&lh[d >> 8], 1);
    }
    __syncthreads();
    part[blockIdx.x * 512 + tid] = lh[tid];
    part[blockIdx.x * 512 + tid + 256] = lh[tid + 256];
}

__global__ void __launch_bounds__(512) bscan_kernel(const int* __restrict__ part,
                                                    int* __restrict__ bbase,
                                                    int* __restrict__ bcursor, int E) {
    __shared__ int sa[512], sb[512];
    int t = threadIdx.x;
    int v = 0;
#pragma unroll 4
    for (int b = 0; b < PHB; b++) v += part[b * 512 + t];
    sa[t] = v;
    __syncthreads();
    int* pa = sa; int* pb = sb;
#pragma unroll
    for (int off = 1; off < 512; off <<= 1) {
        pb[t] = pa[t] + ((t >= off) ? pa[t - off] : 0);
        __syncthreads();
        int* tmp = pa; pa = pb; pb = tmp;
    }
    if (t < NBK) {
        int excl = pa[t] - v;
        bbase[t] = excl;
        bcursor[t] = excl;
    }
    if (t == 0) bbase[NBK] = E;
}

__global__ void __launch_bounds__(256) binscatter_kernel(const int* __restrict__ src,
                                                         const int* __restrict__ dst,
                                                         int* __restrict__ bcursor,
                                                         unsigned int* __restrict__ pairs, int E) {
    __shared__ unsigned int sp[CHUNK];
    __shared__ unsigned short sbof[CHUNK];
    __shared__ int hist[512];
    __shared__ int scanA[512], scanB[512];
    __shared__ int cur[512];
    __shared__ int gbase[512];
    int tid = threadIdx.x;
    int e0 = blockIdx.x * CHUNK;
    int cnt = min(CHUNK, E - e0);

    int dv[CHUNK / 256], sv[CHUNK / 256];
#pragma unroll
    for (int i = 0; i < CHUNK / 256; i++) {
        int idx = tid + i * 256;
        if (idx < cnt) {
            dv[i] = __builtin_nontemporal_load(&dst[e0 + idx]);
            sv[i] = __builtin_nontemporal_load(&src[e0 + idx]);
        }
    }
    hist[tid] = 0; hist[tid + 256] = 0;
    __syncthreads();
#pragma unroll
    for (int i = 0; i < CHUNK / 256; i++) {
        int idx = tid + i * 256;
        if (idx < cnt) atomicAdd(&hist[dv[i] >> 8], 1);
    }
    __syncthreads();
    scanA[tid] = hist[tid]; scanA[tid + 256] = hist[tid + 256];
    __syncthreads();
    int* pa = scanA; int* pb = scanB;
#pragma unroll
    for (int off = 1; off < 512; off <<= 1) {
        pb[tid] = pa[tid] + ((tid >= off) ? pa[tid - off] : 0);
        int t1 = tid + 256;
        pb[t1] = pa[t1] + ((t1 >= off) ? pa[t1 - off] : 0);
        __syncthreads();
        int* tmp = pa; pa = pb; pb = tmp;
    }
    cur[tid] = pa[tid] - hist[tid];
    cur[tid + 256] = pa[tid + 256] - hist[tid + 256];
    __syncthreads();
#pragma unroll
    for (int i = 0; i < CHUNK / 256; i++) {
        int idx = tid + i * 256;
        if (idx < cnt) {
            int b = dv[i] >> 8;
            int lp = atomicAdd(&cur[b], 1);
            sp[lp] = ((unsigned int)(dv[i] & 255) << 24) | (unsigned int)sv[i];
            sbof[lp] = (unsigned short)b;
        }
    }
    {
        int c0 = hist[tid];
        gbase[tid] = c0 ? atomicAdd(&bcursor[tid], c0) : 0;
        int c1 = hist[tid + 256];
        gbase[tid + 256] = c1 ? atomicAdd(&bcursor[tid + 256], c1) : 0;
    }
    __syncthreads();
    for (int i = tid; i < cnt; i += 256) {
        int b = sbof[i];
        int off_in_b = i - (pa[b] - hist[b]);
        pairs[gbase[b] + off_in_b] = sp[i];
    }
}

__global__ void __launch_bounds__(256) bucketsort_kernel(const unsigned int* __restrict__ pairs,
                                                         const int* __restrict__ bbase,
                                                         int* __restrict__ rowptr,
                                                         int* __restrict__ ssrc, int N, int E) {
    __shared__ int hist[256], scanA[256], scanB[256], cur[256];
    int b = blockIdx.x;
    int tid = threadIdx.x;
    int e0 = bbase[b], e1 = bbase[b + 1];
    hist[tid] = 0;
    __syncthreads();
    for (int e = e0 + tid; e < e1; e += 256) {
        unsigned int p = pairs[e];
        atomicAdd(&hist[p >> 24], 1);
    }
    __syncthreads();
    scanA[tid] = hist[tid];
    __syncthreads();
    int* pa = scanA; int* pb = scanB;
#pragma unroll
    for (int off = 1; off < 256; off <<= 1) {
        pb[tid] = pa[tid] + ((tid >= off) ? pa[tid - off] : 0);
        __syncthreads();
        int* tmp = pa; pa = pb; pb = tmp;
    }
    int excl = pa[tid] - hist[tid];
    int node = (b << 8) + tid;
    if (node < N) rowptr[node] = e0 + excl;
    if (b == NBK - 1 && tid == 0) rowptr[N] = E;
    cur[tid] = e0 + excl;
    __syncthreads();
    for (int e = e0 + tid; e < e1; e += 256) {
        unsigned int p = pairs[e];
        int pos = atomicAdd(&cur[p >> 24], 1);
        ssrc[pos] = (int)(p & 0x00FFFFFFu);
    }
}

// ---- W1 -> fp16 transposed [col][k] (once per launch; 16 KB, L2-resident) ----
__global__ void __launch_bounds__(256) cvtw_kernel(const float* __restrict__ W1,
                                                   _Float16* __restrict__ w1t) {
    int t = blockIdx.x * 256 + threadIdx.x;
    if (t < F_IN * H_DIM) {
        int k = t >> 6, col = t & 63;
        w1t[col * F_IN + k] = (_Float16)W1[t];
    }
}

// ---- lin1 via MFMA: 64 rows/block; writes normalized fp16 + norms ----
__global__ void __launch_bounds__(256) lin1_kernel(
        const float* __restrict__ x, const _Float16* __restrict__ w1t,
        const float* __restrict__ b1, _Float16* __restrict__ hnout,
        float* __restrict__ nrmout, int n) {
    __shared__ _Float16 sx[64 * XPAD];
    __shared__ _Float16 sw[64 * XPAD];
    int tid = threadIdx.x;
    int r0 = blockIdx.x * 64;

    for (int ch = tid; ch < 64 * 32; ch += 256) {
        int row = ch >> 5, k4 = (ch & 31) << 2;
        float4 xv = make_float4(0.f, 0.f, 0.f, 0.f);
        if (r0 + row < n) xv = *(const float4*)(x + (size_t)(r0 + row) * F_IN + k4);
        _Float16* p = &sx[row * XPAD + k4];
        p[0] = (_Float16)xv.x; p[1] = (_Float16)xv.y;
        p[2] = (_Float16)xv.z; p[3] = (_Float16)xv.w;
    }
    for (int ch = tid; ch < 64 * 16; ch += 256) {
        int col = ch >> 4, k8 = (ch & 15) << 3;
        *(uint4*)&sw[col * XPAD + k8] = *(const uint4*)(w1t + col * F_IN + k8);
    }
    __syncthreads();

    int w = tid >> 6, lane = tid & 63;
    int q = lane >> 4, c = lane & 15;

    f16x8 afrag[4];
#pragma unroll
    for (int kk = 0; kk < 4; kk++)
        afrag[kk] = *(const f16x8*)&sx[(w * 16 + c) * XPAD + kk * 32 + q * 8];

    f32x4 acc[4] = {{0.f,0.f,0.f,0.f},{0.f,0.f,0.f,0.f},{0.f,0.f,0.f,0.f},{0.f,0.f,0.f,0.f}};
#pragma unroll
    for (int ct = 0; ct < 4; ct++) {
#pragma unroll
        for (int kk = 0; kk < 4; kk++) {
            f16x8 bfrag = *(const f16x8*)&sw[(ct * 16 + c) * XPAD + kk * 32 + q * 8];
            acc[ct] = __builtin_amdgcn_mfma_f32_16x16x32_f16(afrag[kk], bfrag, acc[ct], 0, 0, 0);
        }
    }

    float ss[4] = {0.f, 0.f, 0.f, 0.f};
#pragma unroll
    for (int ct = 0; ct < 4; ct++) {
        float bv = b1[ct * 16 + c];
#pragma unroll
        for (int r = 0; r < 4; r++) {
            float v = fmaxf(acc[ct][r] + bv, 0.0f);
            acc[ct][r] = v;
            ss[r] = fmaf(v, v, ss[r]);
        }
    }
#pragma unroll
    for (int k = 1; k < 16; k <<= 1) {
#pragma unroll
        for (int r = 0; r < 4; r++) ss[r] += __shfl_xor(ss[r], k, 64);
    }
    float nn[4], inv[4];
#pragma unroll
    for (int r = 0; r < 4; r++) {
        nn[r] = fmaxf(sqrtf(ss[r]), 1e-12f);
        inv[r] = 1.0f / nn[r];
    }
#pragma unroll
    for (int ct = 0; ct < 4; ct++)
#pragma unroll
        for (int r = 0; r < 4; r++)
            sx[(w * 16 + q * 4 + r) * XPAD + ct * 16 + c] = (_Float16)(acc[ct][r] * inv[r]);

    if (c == 0) {
#pragma unroll
        for (int r = 0; r < 4; r++) {
            int row = r0 + w * 16 + q * 4 + r;
            if (row < n) nrmout[row] = nn[r];
        }
    }
#pragma unroll
    for (int it = 0; it < 2; it++) {
        int row = w * 16 + it * 8 + (lane >> 3);
        int k8 = (lane & 7) * 8;
        if (r0 + row < n)
            *(uint4*)(hnout + (size_t)(r0 + row) * H_DIM + k8) =
                *(const uint4*)&sx[row * XPAD + k8];
    }
}

// ---- AGNN layer: 8 dst nodes per wave (8 lanes / node) ----
// 3-stage software pipeline, ping-ponged A/B:
//   SLOAD(t+2)  -- ssrc indices two batches ahead
//   HLOAD(t+1)  -- h/nrm gathers one batch ahead
//   COMP(t)     -- compute current batch
// Loop-carried registers force the gathers to stay in flight across each
// compute phase (the scheduler cannot sink a load past its next-iteration
// use). Padding slots clamp to the node's OWN last edge -> duplicate
// cache-line reads, no extra HBM/LLC traffic (R4's global clamp pulled
// random other edges: +37% FETCH).
__global__ void __launch_bounds__(256, 4) agnn_kernel(
        const h8* __restrict__ h, const float* __restrict__ nrm,
        const int* __restrict__ rowptr, const int* __restrict__ ssrc,
        h8* __restrict__ hout, float* __restrict__ nrmout, int n, int E) {
    int wv = (blockIdx.x * blockDim.x + threadIdx.x) >> 6;   // global wave id
    int lane = threadIdx.x & 63;
    int g = lane >> 3;      // node slot 0..7
    int sub = lane & 7;     // feature chunk 0..7
    int wid = wv * 8 + g;   // dst node
    bool nvalid = wid < n;
    int nid = nvalid ? wid : (n - 1);

    int e0 = rowptr[nid];
    int e1 = rowptr[nid + 1];
    int steps = nvalid ? (e1 - e0) : 0;
    int eclamp = min(max(e1 - 1, e0), E - 1);   // node's own last edge (safe for deg 0)

    H8 hd; hd.v = h[(size_t)nid * 8 + sub];
    float ni = nrm[nid];

    // wave-uniform loop bound: max steps over the 8 groups (lane bits 3..5)
    int mx = steps;
    mx = max(mx, __shfl_xor(mx, 8, 64));
    mx = max(mx, __shfl_xor(mx, 16, 64));
    mx = max(mx, __shfl_xor(mx, 32, 64));

    // self loop
    float dself = dpp_red8_add(dot8(hd, hd));
    float wself = __expf(dself);
    float sw = wself;
    float aself = wself * ni;
    half2t ap = {(_Float16)aself, (_Float16)aself};
    half2t acc2[4];
#pragma unroll
    for (int j = 0; j < 4; j++) acc2[j] = ap * hd.p[j];

    int sA[8], sB[8];
    H8 XA[8], XB[8];
    float nA[8], nB[8];

    auto SLOAD = [&](int* s, int ofs) {
#pragma unroll
        for (int k = 0; k < 8; k++) s[k] = ssrc[min(e0 + ofs + k, eclamp)];
    };
    auto HLOAD = [&](const int* s, H8* X, float* xn) {
#pragma unroll
        for (int k = 0; k < 8; k++) {
            X[k].v = h[(size_t)s[k] * 8 + sub];
            xn[k] = nrm[s[k]];
        }
    };
    auto COMP = [&](const H8* X, const float* xn, int base) {
        float d[8];
#pragma unroll
        for (int k = 0; k < 8; k++) d[k] = dpp_red8_add(dot8(X[k], hd));
#pragma unroll
        for (int k = 0; k < 8; k++) {
            float wgt = (base + k < steps) ? __expf(d[k]) : 0.0f;
            sw += wgt;
            float a = wgt * xn[k];
            half2t apk = {(_Float16)a, (_Float16)a};
#pragma unroll
            for (int j = 0; j < 4; j++) acc2[j] += apk * X[k].p[j];
        }
    };

    // prologue
    SLOAD(sA, 0);
    HLOAD(sA, XA, nA);
    SLOAD(sB, 8);
    for (int it = 0; it < mx; it += 16) {
        HLOAD(sB, XB, nB);        // gathers for batch it+8
        SLOAD(sA, it + 16);       // indices for batch it+16
        COMP(XA, nA, it);         // overlaps the two issues above
        HLOAD(sA, XA, nA);        // gathers for batch it+16
        SLOAD(sB, it + 24);       // indices for batch it+24
        COMP(XB, nB, it + 8);     // overlaps the two issues above
    }

    float inv = 1.0f / sw;
    float o[8];
#pragma unroll
    for (int j = 0; j < 4; j++) {
        o[2 * j] = (float)acc2[j][0] * inv;
        o[2 * j + 1] = (float)acc2[j][1] * inv;
    }
    float ss = 0.0f;
#pragma unroll
    for (int i = 0; i < 8; i++) ss = fmaf(o[i], o[i], ss);
    ss = dpp_red8_add(ss);
    float nn = fmaxf(sqrtf(ss), 1e-12f);
    float r = 1.0f / nn;
    h8 oh;
#pragma unroll
    for (int i = 0; i < 8; i++) oh[i] = (_Float16)(o[i] * r);
    if (nvalid) {
        hout[(size_t)wid * 8 + sub] = oh;
        if (sub == 0) nrmout[wid] = nn;
    }
}

// ---- lin2 + log_softmax: normalized fp16 input + per-row norm, LDS-staged ----
__global__ void __launch_bounds__(256) lin2_kernel(
        const h8* __restrict__ h, const float* __restrict__ nrm,
        const float* __restrict__ W2, const float* __restrict__ b2,
        float* __restrict__ out, int n) {
    __shared__ h8 sh[32 * 8];
    __shared__ float snrm[32];
    int tid = threadIdx.x;
    int r0 = blockIdx.x * 32;
    int rows = min(32, n - r0);

    {
        const uint4* hg = (const uint4*)(h + (size_t)r0 * 8);
        uint4* sh4 = (uint4*)sh;
        int tot = rows * 8;
        for (int i = tid; i < tot; i += 256) sh4[i] = hg[i];
        if (tid < rows) snrm[tid] = nrm[r0 + tid];
    }
    __syncthreads();

    int wave = tid >> 6, lane = tid & 63;
    int rbase = wave * 8;

    float acc[8];
    if (lane < C_OUT) {
#pragma unroll
        for (int j = 0; j < 8; j++) acc[j] = 0.0f;
#pragma unroll 2
        for (int k = 0; k < H_DIM; k += 8) {
            float w[8];
#pragma unroll
            for (int i = 0; i < 8; i++) w[i] = W2[(k + i) * C_OUT + lane];
#pragma unroll
            for (int j = 0; j < 8; j++) {
                h8 hv = sh[(rbase + j) * 8 + (k >> 3)];
#pragma unroll
                for (int i = 0; i < 8; i++) acc[j] = fmaf((float)hv[i], w[i], acc[j]);
            }
        }
        float bl = b2[lane];
#pragma unroll
        for (int j = 0; j < 8; j++) acc[j] = fmaf(snrm[rbase + j], acc[j], bl);
    } else {
#pragma unroll
        for (int j = 0; j < 8; j++) acc[j] = -INFINITY;
    }

#pragma unroll
    for (int j = 0; j < 8; j++) {
        int r = rbase + j;
        if (r >= rows) break;
        float m = acc[j];
#pragma unroll
        for (int k = 1; k < 64; k <<= 1) m = fmaxf(m, __shfl_xor(m, k, 64));
        float e = (lane < C_OUT) ? __expf(acc[j] - m) : 0.0f;
        float s = e;
#pragma unroll
        for (int k = 1; k < 64; k <<= 1) s += __shfl_xor(s, k, 64);
        if (lane < C_OUT) out[(size_t)(r0 + r) * C_OUT + lane] = acc[j] - m - logf(s);
    }
}

// ---------------- launch ----------------

extern "C" void kernel_launch(void* const* d_in, const int* in_sizes, int n_in,
                              void* d_out, int out_size, void* d_ws, size_t ws_size,
                              hipStream_t stream) {
    const float* x = (const float*)d_in[0];
    const float* W1 = (const float*)d_in[1];
    const float* b1 = (const float*)d_in[2];
    const float* W2 = (const float*)d_in[3];
    const float* b2 = (const float*)d_in[4];
    const int* ei = (const int*)d_in[5];

    const int N = in_sizes[0] / F_IN;      // 100000
    const int E = in_sizes[5] / 2;         // 1600000
    const int* src = ei;
    const int* dst = ei + E;

    char* w = (char*)d_ws;
    auto carve = [&](size_t bytes) {
        char* p = w;
        w += (bytes + 255) & ~(size_t)255;
        return p;
    };
    _Float16* g1 = (_Float16*)carve((size_t)N * H_DIM * 2);
    _Float16* g2 = (_Float16*)carve((size_t)N * H_DIM * 2);   // aliased as pairs during CSR build
    float* rn1 = (float*)carve((size_t)N * 4);
    float* rn2 = (float*)carve((size_t)N * 4);
    int* rowptr = (int*)carve((size_t)(N + 1) * 4);
    int* bbase = (int*)carve(512 * 4);
    int* bcursor = (int*)carve(512 * 4);
    int* ssrc = (int*)carve((size_t)E * 4);
    _Float16* w1t = (_Float16*)carve((size_t)F_IN * H_DIM * 2);
    unsigned int* pairs = (unsigned int*)g2;  // 6.4 MB alias: dead before agnn layer 1 writes g2
    int* part = (int*)g1;                     // 256 KB alias: dead before lin1 writes g1

    // CSR build: two-level LDS counting sort, stateless (no memset/fill blit)
    bphist_kernel<<<PHB, 256, 0, stream>>>(dst, part, E);
    bscan_kernel<<<1, 512, 0, stream>>>(part, bbase, bcursor, E);
    binscatter_kernel<<<(E + CHUNK - 1) / CHUNK, 256, 0, stream>>>(src, dst, bcursor, pairs, E);
    bucketsort_kernel<<<NBK, 256, 0, stream>>>(pairs, bbase, rowptr, ssrc, N, E);

    // lin1 via MFMA: normalized fp16 rows + norms
    cvtw_kernel<<<(F_IN * H_DIM + 255) / 256, 256, 0, stream>>>(W1, w1t);
    lin1_kernel<<<(N + 63) / 64, 256, 0, stream>>>(x, w1t, b1, g1, rn1, N);

    // 4 AGNN layers, ping-pong on normalized fp16 h (8 nodes/wave -> 32 nodes/block)
    {
        int blocks = (N + 31) / 32;
        agnn_kernel<<<blocks, 256, 0, stream>>>((const h8*)g1, rn1, rowptr, ssrc, (h8*)g2, rn2, N, E);
        agnn_kernel<<<blocks, 256, 0, stream>>>((const h8*)g2, rn2, rowptr, ssrc, (h8*)g1, rn1, N, E);
        agnn_kernel<<<blocks, 256, 0, stream>>>((const h8*)g1, rn1, rowptr, ssrc, (h8*)g2, rn2, N, E);
        agnn_kernel<<<blocks, 256, 0, stream>>>((const h8*)g2, rn2, rowptr, ssrc, (h8*)g1, rn1, N, E);
    }

    // lin2 + log_softmax
    lin2_kernel<<<(N + 31) / 32, 256, 0, stream>>>((const h8*)g1, rn1, W2, b2, (float*)d_out, N);
}

// Round 6
// 247.930 us; speedup vs baseline: 1.1609x; 1.1609x over previous
//
#include <hip/hip_runtime.h>
#include <math.h>

#define F_IN 128
#define H_DIM 64
#define C_OUT 40
#define NBK 391          // ceil(100000/256) coarse buckets, 256 nodes each
#define CHUNK 4096       // edges per binscatter block
#define XPAD 136         // padded LDS half-stride (128 + 8) -> bank spread
#define PHB 128          // partial-histogram blocks (stateless CSR build, no memset)

typedef _Float16 h8 __attribute__((ext_vector_type(8)));   // 16B = 8 fp16 features
typedef _Float16 half2t __attribute__((ext_vector_type(2)));
typedef float nf4 __attribute__((ext_vector_type(4)));     // native float4 (nt-load-able)
typedef _Float16 f16x8 __attribute__((ext_vector_type(8)));
typedef float f32x4 __attribute__((ext_vector_type(4)));

union H8 {
    h8 v;
    half2t p[4];
};

__device__ __forceinline__ float dot8(const H8& a, const H8& b) {
    float d = __builtin_amdgcn_fdot2(a.p[0], b.p[0], 0.0f, false);
    d = __builtin_amdgcn_fdot2(a.p[1], b.p[1], d, false);
    d = __builtin_amdgcn_fdot2(a.p[2], b.p[2], d, false);
    d = __builtin_amdgcn_fdot2(a.p[3], b.p[3], d, false);
    return d;
}

// Butterfly add across the 8 sub-lanes (lane bits 0..2) using DPP only:
// xor1 = quad_perm(1,0,3,2)=0xB1, xor2 = quad_perm(2,3,0,1)=0x4E,
// cross-quad = row_half_mirror (0x141; valid since quads are uniform by then).
__device__ __forceinline__ float dpp_red8_add(float x) {
    int v = __builtin_bit_cast(int, x);
    x += __builtin_bit_cast(float, __builtin_amdgcn_update_dpp(0, v, 0xB1, 0xF, 0xF, true));
    v = __builtin_bit_cast(int, x);
    x += __builtin_bit_cast(float, __builtin_amdgcn_update_dpp(0, v, 0x4E, 0xF, 0xF, true));
    v = __builtin_bit_cast(int, x);
    x += __builtin_bit_cast(float, __builtin_amdgcn_update_dpp(0, v, 0x141, 0xF, 0xF, true));
    return x;
}

// ---------------- CSR build: two-level LDS counting sort ----------------
// pairs packed: (dst&255)<<24 | src   (src < 2^17)

// Stateless partial histogram: each block fully writes its own 512-bin slice
// (plain stores) -> no pre-zeroed global memory, no hipMemsetAsync.
__global__ void __launch_bounds__(256) bphist_kernel(const int* __restrict__ dst,
                                                     int* __restrict__ part, int E) {
    __shared__ int lh[512];
    int tid = threadIdx.x;
    lh[tid] = 0; lh[tid + 256] = 0;
    __syncthreads();
    int slice = (E + PHB - 1) / PHB;
    int lo = blockIdx.x * slice;
    int hi = min(E, lo + slice);
    for (int e = lo + tid; e < hi; e += 256) {
        int d = __builtin_nontemporal_load(&dst[e]);
        atomicAdd(&lh[d >> 8], 1);
    }
    __syncthreads();
    part[blockIdx.x * 512 + tid] = lh[tid];
    part[blockIdx.x * 512 + tid + 256] = lh[tid + 256];
}

__global__ void __launch_bounds__(512) bscan_kernel(const int* __restrict__ part,
                                                    int* __restrict__ bbase,
                                                    int* __restrict__ bcursor, int E) {
    __shared__ int sa[512], sb[512];
    int t = threadIdx.x;
    int v = 0;
#pragma unroll 4
    for (int b = 0; b < PHB; b++) v += part[b * 512 + t];
    sa[t] = v;
    __syncthreads();
    int* pa = sa; int* pb = sb;
#pragma unroll
    for (int off = 1; off < 512; off <<= 1) {
        pb[t] = pa[t] + ((t >= off) ? pa[t - off] : 0);
        __syncthreads();
        int* tmp = pa; pa = pb; pb = tmp;
    }
    if (t < NBK) {
        int excl = pa[t] - v;
        bbase[t] = excl;
        bcursor[t] = excl;
    }
    if (t == 0) bbase[NBK] = E;
}

__global__ void __launch_bounds__(256) binscatter_kernel(const int* __restrict__ src,
                                                         const int* __restrict__ dst,
                                                         int* __restrict__ bcursor,
                                                         unsigned int* __restrict__ pairs, int E) {
    __shared__ unsigned int sp[CHUNK];
    __shared__ unsigned short sbof[CHUNK];
    __shared__ int hist[512];
    __shared__ int scanA[512], scanB[512];
    __shared__ int cur[512];
    __shared__ int gbase[512];
    int tid = threadIdx.x;
    int e0 = blockIdx.x * CHUNK;
    int cnt = min(CHUNK, E - e0);

    int dv[CHUNK / 256], sv[CHUNK / 256];
#pragma unroll
    for (int i = 0; i < CHUNK / 256; i++) {
        int idx = tid + i * 256;
        if (idx < cnt) {
            dv[i] = __builtin_nontemporal_load(&dst[e0 + idx]);
            sv[i] = __builtin_nontemporal_load(&src[e0 + idx]);
        }
    }
    hist[tid] = 0; hist[tid + 256] = 0;
    __syncthreads();
#pragma unroll
    for (int i = 0; i < CHUNK / 256; i++) {
        int idx = tid + i * 256;
        if (idx < cnt) atomicAdd(&hist[dv[i] >> 8], 1);
    }
    __syncthreads();
    scanA[tid] = hist[tid]; scanA[tid + 256] = hist[tid + 256];
    __syncthreads();
    int* pa = scanA; int* pb = scanB;
#pragma unroll
    for (int off = 1; off < 512; off <<= 1) {
        pb[tid] = pa[tid] + ((tid >= off) ? pa[tid - off] : 0);
        int t1 = tid + 256;
        pb[t1] = pa[t1] + ((t1 >= off) ? pa[t1 - off] : 0);
        __syncthreads();
        int* tmp = pa; pa = pb; pb = tmp;
    }
    cur[tid] = pa[tid] - hist[tid];
    cur[tid + 256] = pa[tid + 256] - hist[tid + 256];
    __syncthreads();
#pragma unroll
    for (int i = 0; i < CHUNK / 256; i++) {
        int idx = tid + i * 256;
        if (idx < cnt) {
            int b = dv[i] >> 8;
            int lp = atomicAdd(&cur[b], 1);
            sp[lp] = ((unsigned int)(dv[i] & 255) << 24) | (unsigned int)sv[i];
            sbof[lp] = (unsigned short)b;
        }
    }
    {
        int c0 = hist[tid];
        gbase[tid] = c0 ? atomicAdd(&bcursor[tid], c0) : 0;
        int c1 = hist[tid + 256];
        gbase[tid + 256] = c1 ? atomicAdd(&bcursor[tid + 256], c1) : 0;
    }
    __syncthreads();
    for (int i = tid; i < cnt; i += 256) {
        int b = sbof[i];
        int off_in_b = i - (pa[b] - hist[b]);
        pairs[gbase[b] + off_in_b] = sp[i];
    }
}

__global__ void __launch_bounds__(256) bucketsort_kernel(const unsigned int* __restrict__ pairs,
                                                         const int* __restrict__ bbase,
                                                         int* __restrict__ rowptr,
                                                         int* __restrict__ ssrc, int N, int E) {
    __shared__ int hist[256], scanA[256], scanB[256], cur[256];
    int b = blockIdx.x;
    int tid = threadIdx.x;
    int e0 = bbase[b], e1 = bbase[b + 1];
    hist[tid] = 0;
    __syncthreads();
    for (int e = e0 + tid; e < e1; e += 256) {
        unsigned int p = pairs[e];
        atomicAdd(&hist[p >> 24], 1);
    }
    __syncthreads();
    scanA[tid] = hist[tid];
    __syncthreads();
    int* pa = scanA; int* pb = scanB;
#pragma unroll
    for (int off = 1; off < 256; off <<= 1) {
        pb[tid] = pa[tid] + ((tid >= off) ? pa[tid - off] : 0);
        __syncthreads();
        int* tmp = pa; pa = pb; pb = tmp;
    }
    int excl = pa[tid] - hist[tid];
    int node = (b << 8) + tid;
    if (node < N) rowptr[node] = e0 + excl;
    if (b == NBK - 1 && tid == 0) rowptr[N] = E;
    cur[tid] = e0 + excl;
    __syncthreads();
    for (int e = e0 + tid; e < e1; e += 256) {
        unsigned int p = pairs[e];
        int pos = atomicAdd(&cur[p >> 24], 1);
        ssrc[pos] = (int)(p & 0x00FFFFFFu);
    }
}

// ---- W1 -> fp16 transposed [col][k] (once per launch; 16 KB, L2-resident) ----
__global__ void __launch_bounds__(256) cvtw_kernel(const float* __restrict__ W1,
                                                   _Float16* __restrict__ w1t) {
    int t = blockIdx.x * 256 + threadIdx.x;
    if (t < F_IN * H_DIM) {
        int k = t >> 6, col = t & 63;
        w1t[col * F_IN + k] = (_Float16)W1[t];
    }
}

// ---- lin1 via MFMA: 64 rows/block; writes normalized fp16 + norms ----
__global__ void __launch_bounds__(256) lin1_kernel(
        const float* __restrict__ x, const _Float16* __restrict__ w1t,
        const float* __restrict__ b1, _Float16* __restrict__ hnout,
        float* __restrict__ nrmout, int n) {
    __shared__ _Float16 sx[64 * XPAD];
    __shared__ _Float16 sw[64 * XPAD];
    int tid = threadIdx.x;
    int r0 = blockIdx.x * 64;

    for (int ch = tid; ch < 64 * 32; ch += 256) {
        int row = ch >> 5, k4 = (ch & 31) << 2;
        float4 xv = make_float4(0.f, 0.f, 0.f, 0.f);
        if (r0 + row < n) xv = *(const float4*)(x + (size_t)(r0 + row) * F_IN + k4);
        _Float16* p = &sx[row * XPAD + k4];
        p[0] = (_Float16)xv.x; p[1] = (_Float16)xv.y;
        p[2] = (_Float16)xv.z; p[3] = (_Float16)xv.w;
    }
    for (int ch = tid; ch < 64 * 16; ch += 256) {
        int col = ch >> 4, k8 = (ch & 15) << 3;
        *(uint4*)&sw[col * XPAD + k8] = *(const uint4*)(w1t + col * F_IN + k8);
    }
    __syncthreads();

    int w = tid >> 6, lane = tid & 63;
    int q = lane >> 4, c = lane & 15;

    f16x8 afrag[4];
#pragma unroll
    for (int kk = 0; kk < 4; kk++)
        afrag[kk] = *(const f16x8*)&sx[(w * 16 + c) * XPAD + kk * 32 + q * 8];

    f32x4 acc[4] = {{0.f,0.f,0.f,0.f},{0.f,0.f,0.f,0.f},{0.f,0.f,0.f,0.f},{0.f,0.f,0.f,0.f}};
#pragma unroll
    for (int ct = 0; ct < 4; ct++) {
#pragma unroll
        for (int kk = 0; kk < 4; kk++) {
            f16x8 bfrag = *(const f16x8*)&sw[(ct * 16 + c) * XPAD + kk * 32 + q * 8];
            acc[ct] = __builtin_amdgcn_mfma_f32_16x16x32_f16(afrag[kk], bfrag, acc[ct], 0, 0, 0);
        }
    }

    float ss[4] = {0.f, 0.f, 0.f, 0.f};
#pragma unroll
    for (int ct = 0; ct < 4; ct++) {
        float bv = b1[ct * 16 + c];
#pragma unroll
        for (int r = 0; r < 4; r++) {
            float v = fmaxf(acc[ct][r] + bv, 0.0f);
            acc[ct][r] = v;
            ss[r] = fmaf(v, v, ss[r]);
        }
    }
#pragma unroll
    for (int k = 1; k < 16; k <<= 1) {
#pragma unroll
        for (int r = 0; r < 4; r++) ss[r] += __shfl_xor(ss[r], k, 64);
    }
    float nn[4], inv[4];
#pragma unroll
    for (int r = 0; r < 4; r++) {
        nn[r] = fmaxf(sqrtf(ss[r]), 1e-12f);
        inv[r] = 1.0f / nn[r];
    }
#pragma unroll
    for (int ct = 0; ct < 4; ct++)
#pragma unroll
        for (int r = 0; r < 4; r++)
            sx[(w * 16 + q * 4 + r) * XPAD + ct * 16 + c] = (_Float16)(acc[ct][r] * inv[r]);

    if (c == 0) {
#pragma unroll
        for (int r = 0; r < 4; r++) {
            int row = r0 + w * 16 + q * 4 + r;
            if (row < n) nrmout[row] = nn[r];
        }
    }
#pragma unroll
    for (int it = 0; it < 2; it++) {
        int row = w * 16 + it * 8 + (lane >> 3);
        int k8 = (lane & 7) * 8;
        if (r0 + row < n)
            *(uint4*)(hnout + (size_t)(r0 + row) * H_DIM + k8) =
                *(const uint4*)&sx[row * XPAD + k8];
    }
}

// ---- AGNN layer: 8 dst nodes per wave (8 lanes / node), 8-edge batches ----
// lane = g*8 + sub : group g owns one node, sub owns one 16B feature chunk.
// Per batch: issue 8 clamped ssrc loads + 8 h-gathers + 8 nrm loads, then
// __builtin_amdgcn_sched_barrier(0) pins the scheduling region boundary --
// the machine scheduler CANNOT sink the loads into the compute (it did so
// in R3/R4/R5: VGPR stayed 36-40 = ~2 chains in flight). All 16 gather
// results are live at the barrier -> forced MLP. Padding slots clamp to
// the node's own last edge (same cache line as a real edge: no extra
// traffic, no exec-mask toggles).
__global__ void __launch_bounds__(256, 4) agnn_kernel(
        const h8* __restrict__ h, const float* __restrict__ nrm,
        const int* __restrict__ rowptr, const int* __restrict__ ssrc,
        h8* __restrict__ hout, float* __restrict__ nrmout, int n, int E) {
    int wv = (blockIdx.x * blockDim.x + threadIdx.x) >> 6;   // global wave id
    int lane = threadIdx.x & 63;
    int g = lane >> 3;      // node slot 0..7
    int sub = lane & 7;     // feature chunk 0..7
    int wid = wv * 8 + g;   // dst node
    bool nvalid = wid < n;
    int nid = nvalid ? wid : (n - 1);

    int e0 = rowptr[nid];
    int e1 = rowptr[nid + 1];
    int steps = nvalid ? (e1 - e0) : 0;
    int eclamp = min(max(e1 - 1, e0), E - 1);   // node's own last edge (safe for deg 0)

    H8 hd; hd.v = h[(size_t)nid * 8 + sub];
    float ni = nrm[nid];

    // wave-uniform loop bound: max steps over the 8 groups (lane bits 3..5)
    int mx = steps;
    mx = max(mx, __shfl_xor(mx, 8, 64));
    mx = max(mx, __shfl_xor(mx, 16, 64));
    mx = max(mx, __shfl_xor(mx, 32, 64));

    // self loop
    float dself = dpp_red8_add(dot8(hd, hd));
    float wself = __expf(dself);
    float sw = wself;
    float aself = wself * ni;
    half2t ap = {(_Float16)aself, (_Float16)aself};
    half2t acc2[4];
#pragma unroll
    for (int j = 0; j < 4; j++) acc2[j] = ap * hd.p[j];

    for (int it = 0; it < mx; it += 8) {
        // ---- issue phase: 8 ssrc loads, then 16 gathers, all clustered ----
        int s[8];
#pragma unroll
        for (int k = 0; k < 8; k++) s[k] = ssrc[min(e0 + it + k, eclamp)];
        H8 X[8];
        float xn[8];
#pragma unroll
        for (int k = 0; k < 8; k++) {
            X[k].v = h[(size_t)s[k] * 8 + sub];
            xn[k] = nrm[s[k]];
        }
        // scheduler fence: loads may NOT sink past this point
        __builtin_amdgcn_sched_barrier(0);

        // ---- compute phase ----
        float d[8];
#pragma unroll
        for (int k = 0; k < 8; k++) d[k] = dpp_red8_add(dot8(X[k], hd));
#pragma unroll
        for (int k = 0; k < 8; k++) {
            float wgt = (it + k < steps) ? __expf(d[k]) : 0.0f;
            sw += wgt;
            float a = wgt * xn[k];
            half2t apk = {(_Float16)a, (_Float16)a};
#pragma unroll
            for (int j = 0; j < 4; j++) acc2[j] += apk * X[k].p[j];
        }
    }

    float inv = 1.0f / sw;
    float o[8];
#pragma unroll
    for (int j = 0; j < 4; j++) {
        o[2 * j] = (float)acc2[j][0] * inv;
        o[2 * j + 1] = (float)acc2[j][1] * inv;
    }
    float ss = 0.0f;
#pragma unroll
    for (int i = 0; i < 8; i++) ss = fmaf(o[i], o[i], ss);
    ss = dpp_red8_add(ss);
    float nn = fmaxf(sqrtf(ss), 1e-12f);
    float r = 1.0f / nn;
    h8 oh;
#pragma unroll
    for (int i = 0; i < 8; i++) oh[i] = (_Float16)(o[i] * r);
    if (nvalid) {
        hout[(size_t)wid * 8 + sub] = oh;
        if (sub == 0) nrmout[wid] = nn;
    }
}

// ---- lin2 + log_softmax: normalized fp16 input + per-row norm, LDS-staged ----
__global__ void __launch_bounds__(256) lin2_kernel(
        const h8* __restrict__ h, const float* __restrict__ nrm,
        const float* __restrict__ W2, const float* __restrict__ b2,
        float* __restrict__ out, int n) {
    __shared__ h8 sh[32 * 8];
    __shared__ float snrm[32];
    int tid = threadIdx.x;
    int r0 = blockIdx.x * 32;
    int rows = min(32, n - r0);

    {
        const uint4* hg = (const uint4*)(h + (size_t)r0 * 8);
        uint4* sh4 = (uint4*)sh;
        int tot = rows * 8;
        for (int i = tid; i < tot; i += 256) sh4[i] = hg[i];
        if (tid < rows) snrm[tid] = nrm[r0 + tid];
    }
    __syncthreads();

    int wave = tid >> 6, lane = tid & 63;
    int rbase = wave * 8;

    float acc[8];
    if (lane < C_OUT) {
#pragma unroll
        for (int j = 0; j < 8; j++) acc[j] = 0.0f;
#pragma unroll 2
        for (int k = 0; k < H_DIM; k += 8) {
            float w[8];
#pragma unroll
            for (int i = 0; i < 8; i++) w[i] = W2[(k + i) * C_OUT + lane];
#pragma unroll
            for (int j = 0; j < 8; j++) {
                h8 hv = sh[(rbase + j) * 8 + (k >> 3)];
#pragma unroll
                for (int i = 0; i < 8; i++) acc[j] = fmaf((float)hv[i], w[i], acc[j]);
            }
        }
        float bl = b2[lane];
#pragma unroll
        for (int j = 0; j < 8; j++) acc[j] = fmaf(snrm[rbase + j], acc[j], bl);
    } else {
#pragma unroll
        for (int j = 0; j < 8; j++) acc[j] = -INFINITY;
    }

#pragma unroll
    for (int j = 0; j < 8; j++) {
        int r = rbase + j;
        if (r >= rows) break;
        float m = acc[j];
#pragma unroll
        for (int k = 1; k < 64; k <<= 1) m = fmaxf(m, __shfl_xor(m, k, 64));
        float e = (lane < C_OUT) ? __expf(acc[j] - m) : 0.0f;
        float s = e;
#pragma unroll
        for (int k = 1; k < 64; k <<= 1) s += __shfl_xor(s, k, 64);
        if (lane < C_OUT) out[(size_t)(r0 + r) * C_OUT + lane] = acc[j] - m - logf(s);
    }
}

// ---------------- launch ----------------

extern "C" void kernel_launch(void* const* d_in, const int* in_sizes, int n_in,
                              void* d_out, int out_size, void* d_ws, size_t ws_size,
                              hipStream_t stream) {
    const float* x = (const float*)d_in[0];
    const float* W1 = (const float*)d_in[1];
    const float* b1 = (const float*)d_in[2];
    const float* W2 = (const float*)d_in[3];
    const float* b2 = (const float*)d_in[4];
    const int* ei = (const int*)d_in[5];

    const int N = in_sizes[0] / F_IN;      // 100000
    const int E = in_sizes[5] / 2;         // 1600000
    const int* src = ei;
    const int* dst = ei + E;

    char* w = (char*)d_ws;
    auto carve = [&](size_t bytes) {
        char* p = w;
        w += (bytes + 255) & ~(size_t)255;
        return p;
    };
    _Float16* g1 = (_Float16*)carve((size_t)N * H_DIM * 2);
    _Float16* g2 = (_Float16*)carve((size_t)N * H_DIM * 2);   // aliased as pairs during CSR build
    float* rn1 = (float*)carve((size_t)N * 4);
    float* rn2 = (float*)carve((size_t)N * 4);
    int* rowptr = (int*)carve((size_t)(N + 1) * 4);
    int* bbase = (int*)carve(512 * 4);
    int* bcursor = (int*)carve(512 * 4);
    int* ssrc = (int*)carve((size_t)E * 4);
    _Float16* w1t = (_Float16*)carve((size_t)F_IN * H_DIM * 2);
    unsigned int* pairs = (unsigned int*)g2;  // 6.4 MB alias: dead before agnn layer 1 writes g2
    int* part = (int*)g1;                     // 256 KB alias: dead before lin1 writes g1

    // CSR build: two-level LDS counting sort, stateless (no memset/fill blit)
    bphist_kernel<<<PHB, 256, 0, stream>>>(dst, part, E);
    bscan_kernel<<<1, 512, 0, stream>>>(part, bbase, bcursor, E);
    binscatter_kernel<<<(E + CHUNK - 1) / CHUNK, 256, 0, stream>>>(src, dst, bcursor, pairs, E);
    bucketsort_kernel<<<NBK, 256, 0, stream>>>(pairs, bbase, rowptr, ssrc, N, E);

    // lin1 via MFMA: normalized fp16 rows + norms
    cvtw_kernel<<<(F_IN * H_DIM + 255) / 256, 256, 0, stream>>>(W1, w1t);
    lin1_kernel<<<(N + 63) / 64, 256, 0, stream>>>(x, w1t, b1, g1, rn1, N);

    // 4 AGNN layers, ping-pong on normalized fp16 h (8 nodes/wave -> 32 nodes/block)
    {
        int blocks = (N + 31) / 32;
        agnn_kernel<<<blocks, 256, 0, stream>>>((const h8*)g1, rn1, rowptr, ssrc, (h8*)g2, rn2, N, E);
        agnn_kernel<<<blocks, 256, 0, stream>>>((const h8*)g2, rn2, rowptr, ssrc, (h8*)g1, rn1, N, E);
        agnn_kernel<<<blocks, 256, 0, stream>>>((const h8*)g1, rn1, rowptr, ssrc, (h8*)g2, rn2, N, E);
        agnn_kernel<<<blocks, 256, 0, stream>>>((const h8*)g2, rn2, rowptr, ssrc, (h8*)g1, rn1, N, E);
    }

    // lin2 + log_softmax
    lin2_kernel<<<(N + 31) / 32, 256, 0, stream>>>((const h8*)g1, rn1, W2, b2, (float*)d_out, N);
}

// Round 7
// 246.379 us; speedup vs baseline: 1.1683x; 1.0063x over previous
//
#include <hip/hip_runtime.h>
#include <math.h>

#define F_IN 128
#define H_DIM 64
#define C_OUT 40
#define NBK 391          // ceil(100000/256) coarse buckets, 256 nodes each
#define CHUNK 4096       // edges per binscatter block
#define XPAD 136         // padded LDS half-stride (128 + 8) -> bank spread
#define PHB 128          // partial-histogram blocks (stateless CSR build, no memset)

typedef _Float16 h8 __attribute__((ext_vector_type(8)));   // 16B = 8 fp16 features
typedef _Float16 half2t __attribute__((ext_vector_type(2)));
typedef float nf4 __attribute__((ext_vector_type(4)));     // native float4 (nt-load-able)
typedef _Float16 f16x8 __attribute__((ext_vector_type(8)));
typedef float f32x4 __attribute__((ext_vector_type(4)));

union H8 {
    h8 v;
    half2t p[4];
};

__device__ __forceinline__ float dot8(const H8& a, const H8& b) {
    float d = __builtin_amdgcn_fdot2(a.p[0], b.p[0], 0.0f, false);
    d = __builtin_amdgcn_fdot2(a.p[1], b.p[1], d, false);
    d = __builtin_amdgcn_fdot2(a.p[2], b.p[2], d, false);
    d = __builtin_amdgcn_fdot2(a.p[3], b.p[3], d, false);
    return d;
}

// Butterfly add across the 8 sub-lanes (lane bits 0..2) using DPP only:
// xor1 = quad_perm(1,0,3,2)=0xB1, xor2 = quad_perm(2,3,0,1)=0x4E,
// cross-quad = row_half_mirror (0x141; valid since quads are uniform by then).
__device__ __forceinline__ float dpp_red8_add(float x) {
    int v = __builtin_bit_cast(int, x);
    x += __builtin_bit_cast(float, __builtin_amdgcn_update_dpp(0, v, 0xB1, 0xF, 0xF, true));
    v = __builtin_bit_cast(int, x);
    x += __builtin_bit_cast(float, __builtin_amdgcn_update_dpp(0, v, 0x4E, 0xF, 0xF, true));
    v = __builtin_bit_cast(int, x);
    x += __builtin_bit_cast(float, __builtin_amdgcn_update_dpp(0, v, 0x141, 0xF, 0xF, true));
    return x;
}

// ---------------- CSR build: two-level LDS counting sort ----------------
// pairs packed: (dst&255)<<24 | src   (src < 2^17)

// Stateless partial histogram: each block fully writes its own 512-bin slice
// (plain stores) -> no pre-zeroed global memory, no hipMemsetAsync.
__global__ void __launch_bounds__(256) bphist_kernel(const int* __restrict__ dst,
                                                     int* __restrict__ part, int E) {
    __shared__ int lh[512];
    int tid = threadIdx.x;
    lh[tid] = 0; lh[tid + 256] = 0;
    __syncthreads();
    int slice = (E + PHB - 1) / PHB;
    int lo = blockIdx.x * slice;
    int hi = min(E, lo + slice);
    for (int e = lo + tid; e < hi; e += 256) {
        int d = __builtin_nontemporal_load(&dst[e]);
        atomicAdd(&lh[d >> 8], 1);
    }
    __syncthreads();
    part[blockIdx.x * 512 + tid] = lh[tid];
    part[blockIdx.x * 512 + tid + 256] = lh[tid + 256];
}

__global__ void __launch_bounds__(512) bscan_kernel(const int* __restrict__ part,
                                                    int* __restrict__ bbase,
                                                    int* __restrict__ bcursor, int E) {
    __shared__ int sa[512], sb[512];
    int t = threadIdx.x;
    int v = 0;
#pragma unroll 4
    for (int b = 0; b < PHB; b++) v += part[b * 512 + t];
    sa[t] = v;
    __syncthreads();
    int* pa = sa; int* pb = sb;
#pragma unroll
    for (int off = 1; off < 512; off <<= 1) {
        pb[t] = pa[t] + ((t >= off) ? pa[t - off] : 0);
        __syncthreads();
        int* tmp = pa; pa = pb; pb = tmp;
    }
    if (t < NBK) {
        int excl = pa[t] - v;
        bbase[t] = excl;
        bcursor[t] = excl;
    }
    if (t == 0) bbase[NBK] = E;
}

__global__ void __launch_bounds__(256) binscatter_kernel(const int* __restrict__ src,
                                                         const int* __restrict__ dst,
                                                         int* __restrict__ bcursor,
                                                         unsigned int* __restrict__ pairs, int E) {
    __shared__ unsigned int sp[CHUNK];
    __shared__ unsigned short sbof[CHUNK];
    __shared__ int hist[512];
    __shared__ int scanA[512], scanB[512];
    __shared__ int cur[512];
    __shared__ int gbase[512];
    int tid = threadIdx.x;
    int e0 = blockIdx.x * CHUNK;
    int cnt = min(CHUNK, E - e0);

    int dv[CHUNK / 256], sv[CHUNK / 256];
#pragma unroll
    for (int i = 0; i < CHUNK / 256; i++) {
        int idx = tid + i * 256;
        if (idx < cnt) {
            dv[i] = __builtin_nontemporal_load(&dst[e0 + idx]);
            sv[i] = __builtin_nontemporal_load(&src[e0 + idx]);
        }
    }
    hist[tid] = 0; hist[tid + 256] = 0;
    __syncthreads();
#pragma unroll
    for (int i = 0; i < CHUNK / 256; i++) {
        int idx = tid + i * 256;
        if (idx < cnt) atomicAdd(&hist[dv[i] >> 8], 1);
    }
    __syncthreads();
    scanA[tid] = hist[tid]; scanA[tid + 256] = hist[tid + 256];
    __syncthreads();
    int* pa = scanA; int* pb = scanB;
#pragma unroll
    for (int off = 1; off < 512; off <<= 1) {
        pb[tid] = pa[tid] + ((tid >= off) ? pa[tid - off] : 0);
        int t1 = tid + 256;
        pb[t1] = pa[t1] + ((t1 >= off) ? pa[t1 - off] : 0);
        __syncthreads();
        int* tmp = pa; pa = pb; pb = tmp;
    }
    cur[tid] = pa[tid] - hist[tid];
    cur[tid + 256] = pa[tid + 256] - hist[tid + 256];
    __syncthreads();
#pragma unroll
    for (int i = 0; i < CHUNK / 256; i++) {
        int idx = tid + i * 256;
        if (idx < cnt) {
            int b = dv[i] >> 8;
            int lp = atomicAdd(&cur[b], 1);
            sp[lp] = ((unsigned int)(dv[i] & 255) << 24) | (unsigned int)sv[i];
            sbof[lp] = (unsigned short)b;
        }
    }
    {
        int c0 = hist[tid];
        gbase[tid] = c0 ? atomicAdd(&bcursor[tid], c0) : 0;
        int c1 = hist[tid + 256];
        gbase[tid + 256] = c1 ? atomicAdd(&bcursor[tid + 256], c1) : 0;
    }
    __syncthreads();
    for (int i = tid; i < cnt; i += 256) {
        int b = sbof[i];
        int off_in_b = i - (pa[b] - hist[b]);
        pairs[gbase[b] + off_in_b] = sp[i];
    }
}

__global__ void __launch_bounds__(256) bucketsort_kernel(const unsigned int* __restrict__ pairs,
                                                         const int* __restrict__ bbase,
                                                         int* __restrict__ rowptr,
                                                         int* __restrict__ ssrc, int N, int E) {
    __shared__ int hist[256], scanA[256], scanB[256], cur[256];
    int b = blockIdx.x;
    int tid = threadIdx.x;
    int e0 = bbase[b], e1 = bbase[b + 1];
    hist[tid] = 0;
    __syncthreads();
    for (int e = e0 + tid; e < e1; e += 256) {
        unsigned int p = pairs[e];
        atomicAdd(&hist[p >> 24], 1);
    }
    __syncthreads();
    scanA[tid] = hist[tid];
    __syncthreads();
    int* pa = scanA; int* pb = scanB;
#pragma unroll
    for (int off = 1; off < 256; off <<= 1) {
        pb[tid] = pa[tid] + ((tid >= off) ? pa[tid - off] : 0);
        __syncthreads();
        int* tmp = pa; pa = pb; pb = tmp;
    }
    int excl = pa[tid] - hist[tid];
    int node = (b << 8) + tid;
    if (node < N) rowptr[node] = e0 + excl;
    if (b == NBK - 1 && tid == 0) rowptr[N] = E;
    cur[tid] = e0 + excl;
    __syncthreads();
    for (int e = e0 + tid; e < e1; e += 256) {
        unsigned int p = pairs[e];
        int pos = atomicAdd(&cur[p >> 24], 1);
        ssrc[pos] = (int)(p & 0x00FFFFFFu);
    }
}

// ---- W1 -> fp16 transposed [col][k] (once per launch; 16 KB, L2-resident) ----
__global__ void __launch_bounds__(256) cvtw_kernel(const float* __restrict__ W1,
                                                   _Float16* __restrict__ w1t) {
    int t = blockIdx.x * 256 + threadIdx.x;
    if (t < F_IN * H_DIM) {
        int k = t >> 6, col = t & 63;
        w1t[col * F_IN + k] = (_Float16)W1[t];
    }
}

// ---- lin1 via MFMA: 64 rows/block; writes normalized fp16 + norms ----
__global__ void __launch_bounds__(256) lin1_kernel(
        const float* __restrict__ x, const _Float16* __restrict__ w1t,
        const float* __restrict__ b1, _Float16* __restrict__ hnout,
        float* __restrict__ nrmout, int n) {
    __shared__ _Float16 sx[64 * XPAD];
    __shared__ _Float16 sw[64 * XPAD];
    int tid = threadIdx.x;
    int r0 = blockIdx.x * 64;

    for (int ch = tid; ch < 64 * 32; ch += 256) {
        int row = ch >> 5, k4 = (ch & 31) << 2;
        float4 xv = make_float4(0.f, 0.f, 0.f, 0.f);
        if (r0 + row < n) xv = *(const float4*)(x + (size_t)(r0 + row) * F_IN + k4);
        _Float16* p = &sx[row * XPAD + k4];
        p[0] = (_Float16)xv.x; p[1] = (_Float16)xv.y;
        p[2] = (_Float16)xv.z; p[3] = (_Float16)xv.w;
    }
    for (int ch = tid; ch < 64 * 16; ch += 256) {
        int col = ch >> 4, k8 = (ch & 15) << 3;
        *(uint4*)&sw[col * XPAD + k8] = *(const uint4*)(w1t + col * F_IN + k8);
    }
    __syncthreads();

    int w = tid >> 6, lane = tid & 63;
    int q = lane >> 4, c = lane & 15;

    f16x8 afrag[4];
#pragma unroll
    for (int kk = 0; kk < 4; kk++)
        afrag[kk] = *(const f16x8*)&sx[(w * 16 + c) * XPAD + kk * 32 + q * 8];

    f32x4 acc[4] = {{0.f,0.f,0.f,0.f},{0.f,0.f,0.f,0.f},{0.f,0.f,0.f,0.f},{0.f,0.f,0.f,0.f}};
#pragma unroll
    for (int ct = 0; ct < 4; ct++) {
#pragma unroll
        for (int kk = 0; kk < 4; kk++) {
            f16x8 bfrag = *(const f16x8*)&sw[(ct * 16 + c) * XPAD + kk * 32 + q * 8];
            acc[ct] = __builtin_amdgcn_mfma_f32_16x16x32_f16(afrag[kk], bfrag, acc[ct], 0, 0, 0);
        }
    }

    float ss[4] = {0.f, 0.f, 0.f, 0.f};
#pragma unroll
    for (int ct = 0; ct < 4; ct++) {
        float bv = b1[ct * 16 + c];
#pragma unroll
        for (int r = 0; r < 4; r++) {
            float v = fmaxf(acc[ct][r] + bv, 0.0f);
            acc[ct][r] = v;
            ss[r] = fmaf(v, v, ss[r]);
        }
    }
#pragma unroll
    for (int k = 1; k < 16; k <<= 1) {
#pragma unroll
        for (int r = 0; r < 4; r++) ss[r] += __shfl_xor(ss[r], k, 64);
    }
    float nn[4], inv[4];
#pragma unroll
    for (int r = 0; r < 4; r++) {
        nn[r] = fmaxf(sqrtf(ss[r]), 1e-12f);
        inv[r] = 1.0f / nn[r];
    }
#pragma unroll
    for (int ct = 0; ct < 4; ct++)
#pragma unroll
        for (int r = 0; r < 4; r++)
            sx[(w * 16 + q * 4 + r) * XPAD + ct * 16 + c] = (_Float16)(acc[ct][r] * inv[r]);

    if (c == 0) {
#pragma unroll
        for (int r = 0; r < 4; r++) {
            int row = r0 + w * 16 + q * 4 + r;
            if (row < n) nrmout[row] = nn[r];
        }
    }
#pragma unroll
    for (int it = 0; it < 2; it++) {
        int row = w * 16 + it * 8 + (lane >> 3);
        int k8 = (lane & 7) * 8;
        if (r0 + row < n)
            *(uint4*)(hnout + (size_t)(r0 + row) * H_DIM + k8) =
                *(const uint4*)&sx[row * XPAD + k8];
    }
}

// ---- AGNN layer: 8 dst nodes per wave (8 lanes / node), 8-edge batches ----
// 2-deep software pipeline, regions pinned with sched_barrier(0) (the only
// mechanism that survives the machine scheduler -- R3/R4/R5 evidence):
//   region: { HLOAD(batch t+1) ; SLOAD(indices t+2) }  fence
//   region: { COMP(batch t) }                          fence
// Batch t's gathers are OLDER than t+1's, so the compiler's auto-waitcnt
// before COMP(t) is a counted vmcnt that leaves t+1's 24 loads in flight
// under the compute. Padding slots clamp to the node's own last edge
// (same cache line, no extra traffic). __launch_bounds__(256,3) = 170-VGPR
// budget so both 8xH8 buffers stay live (4-wave budget would spill).
__global__ void __launch_bounds__(256, 3) agnn_kernel(
        const h8* __restrict__ h, const float* __restrict__ nrm,
        const int* __restrict__ rowptr, const int* __restrict__ ssrc,
        h8* __restrict__ hout, float* __restrict__ nrmout, int n, int E) {
    int wv = (blockIdx.x * blockDim.x + threadIdx.x) >> 6;   // global wave id
    int lane = threadIdx.x & 63;
    int g = lane >> 3;      // node slot 0..7
    int sub = lane & 7;     // feature chunk 0..7
    int wid = wv * 8 + g;   // dst node
    bool nvalid = wid < n;
    int nid = nvalid ? wid : (n - 1);

    int e0 = rowptr[nid];
    int e1 = rowptr[nid + 1];
    int steps = nvalid ? (e1 - e0) : 0;
    int eclamp = min(max(e1 - 1, e0), E - 1);   // node's own last edge (safe for deg 0)

    H8 hd; hd.v = h[(size_t)nid * 8 + sub];
    float ni = nrm[nid];

    // wave-uniform loop bound: max steps over the 8 groups (lane bits 3..5)
    int mx = steps;
    mx = max(mx, __shfl_xor(mx, 8, 64));
    mx = max(mx, __shfl_xor(mx, 16, 64));
    mx = max(mx, __shfl_xor(mx, 32, 64));

    // self loop
    float dself = dpp_red8_add(dot8(hd, hd));
    float wself = __expf(dself);
    float sw = wself;
    float aself = wself * ni;
    half2t ap = {(_Float16)aself, (_Float16)aself};
    half2t acc2[4];
#pragma unroll
    for (int j = 0; j < 4; j++) acc2[j] = ap * hd.p[j];

    int sA[8], sB[8];
    H8 XA[8], XB[8];
    float nA[8], nB[8];

    auto SLOAD = [&](int* s, int ofs) {
#pragma unroll
        for (int k = 0; k < 8; k++) s[k] = ssrc[min(e0 + ofs + k, eclamp)];
    };
    auto HLOAD = [&](const int* s, H8* X, float* xn) {
#pragma unroll
        for (int k = 0; k < 8; k++) {
            X[k].v = h[(size_t)s[k] * 8 + sub];
            xn[k] = nrm[s[k]];
        }
    };
    auto COMP = [&](const H8* X, const float* xn, int base) {
        float d[8];
#pragma unroll
        for (int k = 0; k < 8; k++) d[k] = dpp_red8_add(dot8(X[k], hd));
#pragma unroll
        for (int k = 0; k < 8; k++) {
            float wgt = (base + k < steps) ? __expf(d[k]) : 0.0f;
            sw += wgt;
            float a = wgt * xn[k];
            half2t apk = {(_Float16)a, (_Float16)a};
#pragma unroll
            for (int j = 0; j < 4; j++) acc2[j] += apk * X[k].p[j];
        }
    };

    int nb = (mx + 7) >> 3;   // number of real 8-edge batches (wave-uniform)
    // prologue: batch 0 gathers + batch 1 indices
    SLOAD(sA, 0);
    __builtin_amdgcn_sched_barrier(0);
    HLOAD(sA, XA, nA);
    SLOAD(sB, 8);
    __builtin_amdgcn_sched_barrier(0);

    int base = 0;
    for (int b = 0; b < nb; b += 2) {
        // issue batch b+1 gathers + batch b+2 indices; compute batch b
        HLOAD(sB, XB, nB);
        SLOAD(sA, base + 16);
        __builtin_amdgcn_sched_barrier(0);
        COMP(XA, nA, base);
        __builtin_amdgcn_sched_barrier(0);
        if (b + 1 >= nb) break;   // batch b+1 is pure padding: skip compute
        // issue batch b+2 gathers + batch b+3 indices; compute batch b+1
        HLOAD(sA, XA, nA);
        SLOAD(sB, base + 24);
        __builtin_amdgcn_sched_barrier(0);
        COMP(XB, nB, base + 8);
        __builtin_amdgcn_sched_barrier(0);
        base += 16;
    }

    float inv = 1.0f / sw;
    float o[8];
#pragma unroll
    for (int j = 0; j < 4; j++) {
        o[2 * j] = (float)acc2[j][0] * inv;
        o[2 * j + 1] = (float)acc2[j][1] * inv;
    }
    float ss = 0.0f;
#pragma unroll
    for (int i = 0; i < 8; i++) ss = fmaf(o[i], o[i], ss);
    ss = dpp_red8_add(ss);
    float nn = fmaxf(sqrtf(ss), 1e-12f);
    float r = 1.0f / nn;
    h8 oh;
#pragma unroll
    for (int i = 0; i < 8; i++) oh[i] = (_Float16)(o[i] * r);
    if (nvalid) {
        hout[(size_t)wid * 8 + sub] = oh;
        if (sub == 0) nrmout[wid] = nn;
    }
}

// ---- lin2 + log_softmax: normalized fp16 input + per-row norm, LDS-staged ----
__global__ void __launch_bounds__(256) lin2_kernel(
        const h8* __restrict__ h, const float* __restrict__ nrm,
        const float* __restrict__ W2, const float* __restrict__ b2,
        float* __restrict__ out, int n) {
    __shared__ h8 sh[32 * 8];
    __shared__ float snrm[32];
    int tid = threadIdx.x;
    int r0 = blockIdx.x * 32;
    int rows = min(32, n - r0);

    {
        const uint4* hg = (const uint4*)(h + (size_t)r0 * 8);
        uint4* sh4 = (uint4*)sh;
        int tot = rows * 8;
        for (int i = tid; i < tot; i += 256) sh4[i] = hg[i];
        if (tid < rows) snrm[tid] = nrm[r0 + tid];
    }
    __syncthreads();

    int wave = tid >> 6, lane = tid & 63;
    int rbase = wave * 8;

    float acc[8];
    if (lane < C_OUT) {
#pragma unroll
        for (int j = 0; j < 8; j++) acc[j] = 0.0f;
#pragma unroll 2
        for (int k = 0; k < H_DIM; k += 8) {
            float w[8];
#pragma unroll
            for (int i = 0; i < 8; i++) w[i] = W2[(k + i) * C_OUT + lane];
#pragma unroll
            for (int j = 0; j < 8; j++) {
                h8 hv = sh[(rbase + j) * 8 + (k >> 3)];
#pragma unroll
                for (int i = 0; i < 8; i++) acc[j] = fmaf((float)hv[i], w[i], acc[j]);
            }
        }
        float bl = b2[lane];
#pragma unroll
        for (int j = 0; j < 8; j++) acc[j] = fmaf(snrm[rbase + j], acc[j], bl);
    } else {
#pragma unroll
        for (int j = 0; j < 8; j++) acc[j] = -INFINITY;
    }

#pragma unroll
    for (int j = 0; j < 8; j++) {
        int r = rbase + j;
        if (r >= rows) break;
        float m = acc[j];
#pragma unroll
        for (int k = 1; k < 64; k <<= 1) m = fmaxf(m, __shfl_xor(m, k, 64));
        float e = (lane < C_OUT) ? __expf(acc[j] - m) : 0.0f;
        float s = e;
#pragma unroll
        for (int k = 1; k < 64; k <<= 1) s += __shfl_xor(s, k, 64);
        if (lane < C_OUT) out[(size_t)(r0 + r) * C_OUT + lane] = acc[j] - m - logf(s);
    }
}

// ---------------- launch ----------------

extern "C" void kernel_launch(void* const* d_in, const int* in_sizes, int n_in,
                              void* d_out, int out_size, void* d_ws, size_t ws_size,
                              hipStream_t stream) {
    const float* x = (const float*)d_in[0];
    const float* W1 = (const float*)d_in[1];
    const float* b1 = (const float*)d_in[2];
    const float* W2 = (const float*)d_in[3];
    const float* b2 = (const float*)d_in[4];
    const int* ei = (const int*)d_in[5];

    const int N = in_sizes[0] / F_IN;      // 100000
    const int E = in_sizes[5] / 2;         // 1600000
    const int* src = ei;
    const int* dst = ei + E;

    char* w = (char*)d_ws;
    auto carve = [&](size_t bytes) {
        char* p = w;
        w += (bytes + 255) & ~(size_t)255;
        return p;
    };
    _Float16* g1 = (_Float16*)carve((size_t)N * H_DIM * 2);
    _Float16* g2 = (_Float16*)carve((size_t)N * H_DIM * 2);   // aliased as pairs during CSR build
    float* rn1 = (float*)carve((size_t)N * 4);
    float* rn2 = (float*)carve((size_t)N * 4);
    int* rowptr = (int*)carve((size_t)(N + 1) * 4);
    int* bbase = (int*)carve(512 * 4);
    int* bcursor = (int*)carve(512 * 4);
    int* ssrc = (int*)carve((size_t)E * 4);
    _Float16* w1t = (_Float16*)carve((size_t)F_IN * H_DIM * 2);
    unsigned int* pairs = (unsigned int*)g2;  // 6.4 MB alias: dead before agnn layer 1 writes g2
    int* part = (int*)g1;                     // 256 KB alias: dead before lin1 writes g1

    // CSR build: two-level LDS counting sort, stateless (no memset/fill blit)
    bphist_kernel<<<PHB, 256, 0, stream>>>(dst, part, E);
    bscan_kernel<<<1, 512, 0, stream>>>(part, bbase, bcursor, E);
    binscatter_kernel<<<(E + CHUNK - 1) / CHUNK, 256, 0, stream>>>(src, dst, bcursor, pairs, E);
    bucketsort_kernel<<<NBK, 256, 0, stream>>>(pairs, bbase, rowptr, ssrc, N, E);

    // lin1 via MFMA: normalized fp16 rows + norms
    cvtw_kernel<<<(F_IN * H_DIM + 255) / 256, 256, 0, stream>>>(W1, w1t);
    lin1_kernel<<<(N + 63) / 64, 256, 0, stream>>>(x, w1t, b1, g1, rn1, N);

    // 4 AGNN layers, ping-pong on normalized fp16 h (8 nodes/wave -> 32 nodes/block)
    {
        int blocks = (N + 31) / 32;
        agnn_kernel<<<blocks, 256, 0, stream>>>((const h8*)g1, rn1, rowptr, ssrc, (h8*)g2, rn2, N, E);
        agnn_kernel<<<blocks, 256, 0, stream>>>((const h8*)g2, rn2, rowptr, ssrc, (h8*)g1, rn1, N, E);
        agnn_kernel<<<blocks, 256, 0, stream>>>((const h8*)g1, rn1, rowptr, ssrc, (h8*)g2, rn2, N, E);
        agnn_kernel<<<blocks, 256, 0, stream>>>((const h8*)g2, rn2, rowptr, ssrc, (h8*)g1, rn1, N, E);
    }

    // lin2 + log_softmax
    lin2_kernel<<<(N + 31) / 32, 256, 0, stream>>>((const h8*)g1, rn1, W2, b2, (float*)d_out, N);
}